// Round 1
// baseline (2005.174 us; speedup 1.0000x reference)
//
#include <hip/hip_runtime.h>
#include <math.h>

#define IN_DIM 128
#define HID 64
#define HEADS 4
#define HH 256   // HEADS*HID
#define OUT_DIM 64
#define NEG_SLOPE 0.2f

__device__ __forceinline__ float elu_f(float x){ return x > 0.f ? x : (expf(x) - 1.f); }
__device__ __forceinline__ float lrelu_f(float x){ return x > 0.f ? x : NEG_SLOPE * x; }

__device__ __forceinline__ void atomicMaxFloat(float* addr, float val){
  if (val >= 0.f) atomicMax((int*)addr, __float_as_int(val));
  else            atomicMin((unsigned int*)addr, __float_as_uint(val));
}

// ---- shared input projection: rows 0..n_user-1 from xu -> hu, rest from xp -> hp
// block = 256 threads, 16 rows/block. LDS-staged x rows, W column-broadcast.
__global__ void proj_kernel(const float* __restrict__ xu, const float* __restrict__ xp,
                            const float* __restrict__ W, const float* __restrict__ b,
                            float* __restrict__ hu, float* __restrict__ hp,
                            int n_user, int n_total){
  __shared__ float xs[16 * IN_DIM];
  int row0 = blockIdx.x * 16;
  for (int i = threadIdx.x; i < 16 * IN_DIM; i += 256){
    int r = row0 + i / IN_DIM;
    float v = 0.f;
    if (r < n_total){
      int k = i % IN_DIM;
      v = (r < n_user) ? xu[(size_t)r * IN_DIM + k] : xp[(size_t)(r - n_user) * IN_DIM + k];
    }
    xs[i] = v;
  }
  __syncthreads();
  int c = threadIdx.x & 63;
  int g = threadIdx.x >> 6;       // 4 groups, 4 rows each
  float acc[4] = {0.f, 0.f, 0.f, 0.f};
  for (int k = 0; k < IN_DIM; ++k){
    float wv = W[k * HID + c];
    #pragma unroll
    for (int r = 0; r < 4; ++r) acc[r] += xs[(g * 4 + r) * IN_DIM + k] * wv;
  }
  float bb = b[c];
  #pragma unroll
  for (int r = 0; r < 4; ++r){
    int rr = row0 + g * 4 + r;
    if (rr < n_total){
      float v = acc[r] + bb;
      if (rr < n_user) hu[(size_t)rr * HID + c] = v;
      else             hp[(size_t)(rr - n_user) * HID + c] = v;
    }
  }
}

// ---- fold attention vectors: w_s[h*64+k] = sum_c lin[k, h*64+c]*att_s[h,c]; same for w_d
__global__ void fold_kernel(const float* __restrict__ lin, const float* __restrict__ att_s,
                            const float* __restrict__ att_d,
                            float* __restrict__ w_s, float* __restrict__ w_d){
  int t = threadIdx.x;          // 256 threads: h = t>>6, k = t&63
  int h = t >> 6, k = t & 63;
  float as = 0.f, ad = 0.f;
  for (int c = 0; c < HID; ++c){
    float lv = lin[k * HH + h * HID + c];
    as += lv * att_s[h * HID + c];
    ad += lv * att_d[h * HID + c];
  }
  w_s[t] = as; w_d[t] = ad;
}

// ---- hs_lin = h_src @ lin  ([n,64] @ [64,256]); block 256 thr, 8 rows/block
__global__ void hslin_kernel(const float* __restrict__ h, const float* __restrict__ lin,
                             float* __restrict__ out, int n){
  __shared__ float hsm[8 * HID];
  int row0 = blockIdx.x * 8;
  for (int i = threadIdx.x; i < 8 * HID; i += 256){
    int r = row0 + i / HID;
    hsm[i] = (r < n) ? h[(size_t)r * HID + (i & 63)] : 0.f;
  }
  __syncthreads();
  int c = threadIdx.x;          // 0..255 output col
  float acc[8] = {};
  for (int k = 0; k < HID; ++k){
    float lv = lin[k * HH + c];
    #pragma unroll
    for (int r = 0; r < 8; ++r) acc[r] += hsm[r * HID + k] * lv;
  }
  #pragma unroll
  for (int r = 0; r < 8; ++r){
    int rr = row0 + r;
    if (rr < n) out[(size_t)rr * HH + c] = acc[r];
  }
}

// ---- per-node attention scalars: wave per (node, role)
__global__ void att_node_kernel(const float* __restrict__ h_src, const float* __restrict__ h_dst,
                                const float* __restrict__ w_s, const float* __restrict__ w_d,
                                float* __restrict__ a_s, float* __restrict__ a_d,
                                int n_src, int n_dst){
  int wave = (int)((blockIdx.x * (size_t)blockDim.x + threadIdx.x) >> 6);
  int lane = threadIdx.x & 63;
  const float* hptr; const float* wptr; float* optr; int n;
  if (wave < n_src){ hptr = h_src; wptr = w_s; optr = a_s; n = wave; }
  else {
    int w2 = wave - n_src;
    if (w2 >= n_dst) return;
    hptr = h_dst; wptr = w_d; optr = a_d; n = w2;
  }
  float hv = hptr[(size_t)n * HID + lane];
  #pragma unroll
  for (int hh = 0; hh < HEADS; ++hh){
    float p = hv * wptr[hh * HID + lane];
    #pragma unroll
    for (int off = 32; off > 0; off >>= 1) p += __shfl_xor(p, off, 64);
    if (lane == 0) optr[(size_t)n * HEADS + hh] = p;
  }
}

__global__ void fill_kernel(float* __restrict__ p, float v, int n){
  int i = blockIdx.x * blockDim.x + threadIdx.x;
  if (i < n) p[i] = v;
}

// ---- pass 1: e = leaky_relu(a_s[src]+a_d[dst]); store e; atomic segment max
__global__ void edge_max_kernel(const int* __restrict__ src, const int* __restrict__ dst,
                                const float* __restrict__ a_s, const float* __restrict__ a_d,
                                float* __restrict__ m, float* __restrict__ e_out, int E_){
  int e = blockIdx.x * blockDim.x + threadIdx.x;
  if (e >= E_) return;
  int s = src[e], d = dst[e];
  float4 as = *(const float4*)(a_s + (size_t)s * 4);
  float4 ad = *(const float4*)(a_d + (size_t)d * 4);
  float v0 = lrelu_f(as.x + ad.x), v1 = lrelu_f(as.y + ad.y);
  float v2 = lrelu_f(as.z + ad.z), v3 = lrelu_f(as.w + ad.w);
  *(float4*)(e_out + (size_t)e * 4) = make_float4(v0, v1, v2, v3);
  atomicMaxFloat(m + (size_t)d * 4 + 0, v0);
  atomicMaxFloat(m + (size_t)d * 4 + 1, v1);
  atomicMaxFloat(m + (size_t)d * 4 + 2, v2);
  atomicMaxFloat(m + (size_t)d * 4 + 3, v3);
}

// ---- pass 2: ex = exp(e - m[dst]); store ex; atomic segment sum
__global__ void edge_sum_kernel(const int* __restrict__ dst, const float* __restrict__ m,
                                float* __restrict__ ex, float* __restrict__ s_sum, int E_){
  int e = blockIdx.x * blockDim.x + threadIdx.x;
  if (e >= E_) return;
  int d = dst[e];
  float4 ev = *(const float4*)(ex + (size_t)e * 4);
  float4 mv = *(const float4*)(m + (size_t)d * 4);
  float x0 = expf(ev.x - mv.x), x1 = expf(ev.y - mv.y);
  float x2 = expf(ev.z - mv.z), x3 = expf(ev.w - mv.w);
  *(float4*)(ex + (size_t)e * 4) = make_float4(x0, x1, x2, x3);
  atomicAdd(s_sum + (size_t)d * 4 + 0, x0);
  atomicAdd(s_sum + (size_t)d * 4 + 1, x1);
  atomicAdd(s_sum + (size_t)d * 4 + 2, x2);
  atomicAdd(s_sum + (size_t)d * 4 + 3, x3);
}

// ---- pass 3: acc[dst] += alpha * hs_lin[src]; one block (256 thr) per edge
__global__ void scatter_kernel(const int* __restrict__ src, const int* __restrict__ dst,
                               const float* __restrict__ hs_lin, const float* __restrict__ ex,
                               const float* __restrict__ s_sum, float* __restrict__ acc, int E_){
  int e = blockIdx.x;
  if (e >= E_) return;
  int c = threadIdx.x;
  int h = c >> 6;
  int s = src[e], d = dst[e];
  float alpha = ex[(size_t)e * 4 + h] / (s_sum[(size_t)d * 4 + h] + 1e-16f);
  float v = hs_lin[(size_t)s * HH + c] * alpha;
  atomicAdd(acc + (size_t)d * HH + c, v);
}

// ---- user epilogue: elu(acc + b1 + b2) @ W_out + b_out ; block 256, 4 rows
__global__ void out_user_kernel(const float* __restrict__ acc, const float* __restrict__ b1,
                                const float* __restrict__ b2, const float* __restrict__ Wo,
                                const float* __restrict__ bo, float* __restrict__ out, int n){
  __shared__ float tmp[4 * HH];
  int row0 = blockIdx.x * 4;
  for (int r = 0; r < 4; ++r){
    int rr = row0 + r;
    float v = 0.f;
    if (rr < n)
      v = elu_f(acc[(size_t)rr * HH + threadIdx.x] + b1[threadIdx.x] + b2[threadIdx.x]);
    tmp[r * HH + threadIdx.x] = v;
  }
  __syncthreads();
  int c = threadIdx.x & 63, g = threadIdx.x >> 6;
  float s = 0.f;
  for (int k = 0; k < HH; ++k) s += tmp[g * HH + k] * Wo[k * OUT_DIM + c];
  int rr = row0 + g;
  if (rr < n) out[(size_t)rr * OUT_DIM + c] = s + bo[c];
}

// ---- post epilogue: elementwise elu(acc + bias)
__global__ void out_post_kernel(const float* __restrict__ acc, const float* __restrict__ bias,
                                float* __restrict__ out, size_t total){
  size_t i = (size_t)blockIdx.x * blockDim.x + threadIdx.x;
  if (i >= total) return;
  out[i] = elu_f(acc[i] + bias[i & 255]);
}

extern "C" void kernel_launch(void* const* d_in, const int* in_sizes, int n_in,
                              void* d_out, int out_size, void* d_ws, size_t ws_size,
                              hipStream_t stream){
  const float* xu = (const float*)d_in[0];
  const float* xp = (const float*)d_in[1];
  const float* Wp = (const float*)d_in[8];
  const float* bp = (const float*)d_in[9];
  const float* Wo = (const float*)d_in[22];
  const float* bo = (const float*)d_in[23];

  const int n_user = in_sizes[0] / IN_DIM;
  const int n_post = in_sizes[1] / IN_DIM;
  const int n_max  = n_user > n_post ? n_user : n_post;
  float* out = (float*)d_out;

  // workspace layout (fp32)
  float* ws = (float*)d_ws;
  size_t off = 0;
  float* hu       = ws + off; off += (size_t)n_user * HID;
  float* hp       = ws + off; off += (size_t)n_post * HID;
  float* acc_user = ws + off; off += (size_t)n_user * HH;
  float* acc_post = ws + off; off += (size_t)n_post * HH;
  float* hs_lin   = ws + off; off += (size_t)n_max * HH;
  float* a_s      = ws + off; off += (size_t)n_max * HEADS;
  float* a_d      = ws + off; off += (size_t)n_max * HEADS;
  float* m_buf    = ws + off; off += (size_t)n_max * HEADS;
  float* s_buf    = ws + off; off += (size_t)n_max * HEADS;
  float* w_s      = ws + off; off += HH;
  float* w_d      = ws + off; off += HH;
  float* ex_buf   = ws + off; // E*4 floats, E read per type below

  hipMemsetAsync(acc_user, 0, (size_t)n_user * HH * sizeof(float), stream);
  hipMemsetAsync(acc_post, 0, (size_t)n_post * HH * sizeof(float), stream);

  int n_total = n_user + n_post;
  proj_kernel<<<(n_total + 15) / 16, 256, 0, stream>>>(xu, xp, Wp, bp, hu, hp, n_user, n_total);

  // per-edge-type config: {src_idx, lin_idx, h_src, h_dst, n_src, n_dst, acc}
  for (int t = 0; t < 3; ++t){
    const int*   src;  const int* dst;
    const float *lin, *att_s, *att_d;
    const float *h_src, *h_dst;
    int n_src, n_dst, E_;
    float* acc;
    if (t == 0){        // u2u
      src = (const int*)d_in[2]; dst = (const int*)d_in[3]; E_ = in_sizes[2];
      lin = (const float*)d_in[10]; att_s = (const float*)d_in[11]; att_d = (const float*)d_in[12];
      h_src = hu; h_dst = hu; n_src = n_user; n_dst = n_user; acc = acc_user;
    } else if (t == 1){ // p2u
      src = (const int*)d_in[4]; dst = (const int*)d_in[5]; E_ = in_sizes[4];
      lin = (const float*)d_in[14]; att_s = (const float*)d_in[15]; att_d = (const float*)d_in[16];
      h_src = hp; h_dst = hu; n_src = n_post; n_dst = n_user; acc = acc_user;
    } else {            // u2p
      src = (const int*)d_in[6]; dst = (const int*)d_in[7]; E_ = in_sizes[6];
      lin = (const float*)d_in[18]; att_s = (const float*)d_in[19]; att_d = (const float*)d_in[20];
      h_src = hu; h_dst = hp; n_src = n_user; n_dst = n_post; acc = acc_post;
    }

    fold_kernel<<<1, 256, 0, stream>>>(lin, att_s, att_d, w_s, w_d);
    hslin_kernel<<<(n_src + 7) / 8, 256, 0, stream>>>(h_src, lin, hs_lin, n_src);
    att_node_kernel<<<(n_src + n_dst + 3) / 4, 256, 0, stream>>>(h_src, h_dst, w_s, w_d, a_s, a_d, n_src, n_dst);
    fill_kernel<<<(n_dst * HEADS + 255) / 256, 256, 0, stream>>>(m_buf, -INFINITY, n_dst * HEADS);
    hipMemsetAsync(s_buf, 0, (size_t)n_dst * HEADS * sizeof(float), stream);
    edge_max_kernel<<<(E_ + 255) / 256, 256, 0, stream>>>(src, dst, a_s, a_d, m_buf, ex_buf, E_);
    edge_sum_kernel<<<(E_ + 255) / 256, 256, 0, stream>>>(dst, m_buf, ex_buf, s_buf, E_);
    scatter_kernel<<<E_, 256, 0, stream>>>(src, dst, hs_lin, ex_buf, s_buf, acc, E_);
  }

  out_user_kernel<<<(n_user + 3) / 4, 256, 0, stream>>>(
      acc_user, (const float*)d_in[13], (const float*)d_in[17], Wo, bo, out, n_user);
  out_post_kernel<<<((size_t)n_post * HH + 255) / 256, 256, 0, stream>>>(
      acc_post, (const float*)d_in[21], out + (size_t)n_user * OUT_DIM, (size_t)n_post * HH);
}

// Round 2
// 982.685 us; speedup vs baseline: 2.0405x; 2.0405x over previous
//
#include <hip/hip_runtime.h>
#include <math.h>

#define IN_DIM 128
#define HID 64
#define HEADS 4
#define HH 256   // HEADS*HID
#define OUT_DIM 64
#define NEG_SLOPE 0.2f

__device__ __forceinline__ float elu_f(float x){ return x > 0.f ? x : (expf(x) - 1.f); }
__device__ __forceinline__ float lrelu_f(float x){ return x > 0.f ? x : NEG_SLOPE * x; }

// ---- shared input projection: rows 0..n_user-1 from xu -> hu, rest from xp -> hp
__global__ void proj_kernel(const float* __restrict__ xu, const float* __restrict__ xp,
                            const float* __restrict__ W, const float* __restrict__ b,
                            float* __restrict__ hu, float* __restrict__ hp,
                            int n_user, int n_total){
  __shared__ float xs[16 * IN_DIM];
  int row0 = blockIdx.x * 16;
  for (int i = threadIdx.x; i < 16 * IN_DIM; i += 256){
    int r = row0 + i / IN_DIM;
    float v = 0.f;
    if (r < n_total){
      int k = i % IN_DIM;
      v = (r < n_user) ? xu[(size_t)r * IN_DIM + k] : xp[(size_t)(r - n_user) * IN_DIM + k];
    }
    xs[i] = v;
  }
  __syncthreads();
  int c = threadIdx.x & 63;
  int g = threadIdx.x >> 6;
  float acc[4] = {0.f, 0.f, 0.f, 0.f};
  for (int k = 0; k < IN_DIM; ++k){
    float wv = W[k * HID + c];
    #pragma unroll
    for (int r = 0; r < 4; ++r) acc[r] += xs[(g * 4 + r) * IN_DIM + k] * wv;
  }
  float bb = b[c];
  #pragma unroll
  for (int r = 0; r < 4; ++r){
    int rr = row0 + g * 4 + r;
    if (rr < n_total){
      float v = acc[r] + bb;
      if (rr < n_user) hu[(size_t)rr * HID + c] = v;
      else             hp[(size_t)(rr - n_user) * HID + c] = v;
    }
  }
}

// ---- fold attention vectors: w_s[h*64+k] = sum_c lin[k, h*64+c]*att_s[h,c]
__global__ void fold_kernel(const float* __restrict__ lin, const float* __restrict__ att_s,
                            const float* __restrict__ att_d,
                            float* __restrict__ w_s, float* __restrict__ w_d){
  int t = threadIdx.x;
  int h = t >> 6, k = t & 63;
  float as = 0.f, ad = 0.f;
  for (int c = 0; c < HID; ++c){
    float lv = lin[k * HH + h * HID + c];
    as += lv * att_s[h * HID + c];
    ad += lv * att_d[h * HID + c];
  }
  w_s[t] = as; w_d[t] = ad;
}

// ---- hs_lin = h_src @ lin  ([n,64] @ [64,256]); block 256 thr, 8 rows/block
__global__ void hslin_kernel(const float* __restrict__ h, const float* __restrict__ lin,
                             float* __restrict__ out, int n){
  __shared__ float hsm[8 * HID];
  int row0 = blockIdx.x * 8;
  for (int i = threadIdx.x; i < 8 * HID; i += 256){
    int r = row0 + i / HID;
    hsm[i] = (r < n) ? h[(size_t)r * HID + (i & 63)] : 0.f;
  }
  __syncthreads();
  int c = threadIdx.x;
  float acc[8] = {};
  for (int k = 0; k < HID; ++k){
    float lv = lin[k * HH + c];
    #pragma unroll
    for (int r = 0; r < 8; ++r) acc[r] += hsm[r * HID + k] * lv;
  }
  #pragma unroll
  for (int r = 0; r < 8; ++r){
    int rr = row0 + r;
    if (rr < n) out[(size_t)rr * HH + c] = acc[r];
  }
}

// ---- per-node attention scalars: wave per (node, role)
__global__ void att_node_kernel(const float* __restrict__ h_src, const float* __restrict__ h_dst,
                                const float* __restrict__ w_s, const float* __restrict__ w_d,
                                float* __restrict__ a_s, float* __restrict__ a_d,
                                int n_src, int n_dst){
  int wave = (int)((blockIdx.x * (size_t)blockDim.x + threadIdx.x) >> 6);
  int lane = threadIdx.x & 63;
  const float* hptr; const float* wptr; float* optr; int n;
  if (wave < n_src){ hptr = h_src; wptr = w_s; optr = a_s; n = wave; }
  else {
    int w2 = wave - n_src;
    if (w2 >= n_dst) return;
    hptr = h_dst; wptr = w_d; optr = a_d; n = w2;
  }
  float hv = hptr[(size_t)n * HID + lane];
  #pragma unroll
  for (int hh = 0; hh < HEADS; ++hh){
    float p = hv * wptr[hh * HID + lane];
    #pragma unroll
    for (int off = 32; off > 0; off >>= 1) p += __shfl_xor(p, off, 64);
    if (lane == 0) optr[(size_t)n * HEADS + hh] = p;
  }
}

// ======== CSR build ========
__global__ void hist_kernel(const int* __restrict__ dst, int* __restrict__ deg, int E_){
  int e = blockIdx.x * blockDim.x + threadIdx.x;
  if (e < E_) atomicAdd(deg + dst[e], 1);
}

// block-wise exclusive scan (256/block); writes partial excl + block sums
__global__ void scan1_kernel(const int* __restrict__ deg, int* __restrict__ offs,
                             int* __restrict__ bsum, int n){
  __shared__ int sm[256];
  int i = blockIdx.x * 256 + threadIdx.x;
  int v = (i < n) ? deg[i] : 0;
  sm[threadIdx.x] = v;
  __syncthreads();
  for (int off = 1; off < 256; off <<= 1){
    int t = (threadIdx.x >= off) ? sm[threadIdx.x - off] : 0;
    __syncthreads();
    sm[threadIdx.x] += t;
    __syncthreads();
  }
  if (i < n) offs[i] = sm[threadIdx.x] - v;
  if (threadIdx.x == 255) bsum[blockIdx.x] = sm[255];
}

// single-block exclusive scan of block sums (nb <= 256)
__global__ void scan2_kernel(int* __restrict__ bsum, int nb){
  __shared__ int sm[256];
  int v = (threadIdx.x < nb) ? bsum[threadIdx.x] : 0;
  sm[threadIdx.x] = v;
  __syncthreads();
  for (int off = 1; off < 256; off <<= 1){
    int t = (threadIdx.x >= off) ? sm[threadIdx.x - off] : 0;
    __syncthreads();
    sm[threadIdx.x] += t;
    __syncthreads();
  }
  if (threadIdx.x < nb) bsum[threadIdx.x] = sm[threadIdx.x] - v;
}

__global__ void scan3_kernel(int* __restrict__ offs, int* __restrict__ cursor,
                             const int* __restrict__ bsum, int n){
  int i = blockIdx.x * 256 + threadIdx.x;
  if (i >= n) return;
  int o = offs[i] + bsum[blockIdx.x];
  offs[i] = o;
  cursor[i] = o;
}

__global__ void csrfill_kernel(const int* __restrict__ src, const int* __restrict__ dst,
                               int* __restrict__ cursor, int* __restrict__ csr_src, int E_){
  int e = blockIdx.x * blockDim.x + threadIdx.x;
  if (e >= E_) return;
  int pos = atomicAdd(cursor + dst[e], 1);
  csr_src[pos] = src[e];
}

// ---- per-dst softmax stats: m[d][h], s[d][h]
__global__ void stats_kernel(const int* __restrict__ csr_src, const int* __restrict__ offs,
                             const int* __restrict__ deg,
                             const float* __restrict__ a_s, const float* __restrict__ a_d,
                             float* __restrict__ m_buf, float* __restrict__ s_buf, int n_dst){
  int d = blockIdx.x * blockDim.x + threadIdx.x;
  if (d >= n_dst) return;
  int base = offs[d], n = deg[d];
  float4 ad = *(const float4*)(a_d + (size_t)d * 4);
  float m0 = -INFINITY, m1 = -INFINITY, m2 = -INFINITY, m3 = -INFINITY;
  for (int j = 0; j < n; ++j){
    int s = csr_src[base + j];
    float4 as = *(const float4*)(a_s + (size_t)s * 4);
    m0 = fmaxf(m0, lrelu_f(as.x + ad.x));
    m1 = fmaxf(m1, lrelu_f(as.y + ad.y));
    m2 = fmaxf(m2, lrelu_f(as.z + ad.z));
    m3 = fmaxf(m3, lrelu_f(as.w + ad.w));
  }
  float s0 = 0.f, s1 = 0.f, s2 = 0.f, s3 = 0.f;
  for (int j = 0; j < n; ++j){
    int s = csr_src[base + j];
    float4 as = *(const float4*)(a_s + (size_t)s * 4);
    s0 += expf(lrelu_f(as.x + ad.x) - m0);
    s1 += expf(lrelu_f(as.y + ad.y) - m1);
    s2 += expf(lrelu_f(as.z + ad.z) - m2);
    s3 += expf(lrelu_f(as.w + ad.w) - m3);
  }
  *(float4*)(m_buf + (size_t)d * 4) = make_float4(m0, m1, m2, m3);
  *(float4*)(s_buf + (size_t)d * 4) = make_float4(s0, s1, s2, s3);
}

// ---- gather: block 256 per dst; acc[d][c] = sum_j alpha_j * hs_lin[src_j][c]
template<int ACCUM>
__global__ void gather_kernel(const int* __restrict__ csr_src, const int* __restrict__ offs,
                              const int* __restrict__ deg,
                              const float* __restrict__ hs_lin,
                              const float* __restrict__ a_s, const float* __restrict__ a_d,
                              const float* __restrict__ m_buf, const float* __restrict__ s_buf,
                              float* __restrict__ acc, int n_dst){
  __shared__ int srcs[128];
  int d = blockIdx.x;
  if (d >= n_dst) return;
  int c = threadIdx.x;
  int h = c >> 6;
  int base = offs[d], n = deg[d];
  float adv = a_d[(size_t)d * 4 + h];
  float mv  = m_buf[(size_t)d * 4 + h];
  float sinv = 1.f / (s_buf[(size_t)d * 4 + h] + 1e-16f);
  float a = 0.f;
  for (int j0 = 0; j0 < n; j0 += 128){
    int chunk = n - j0; if (chunk > 128) chunk = 128;
    __syncthreads();
    for (int j = threadIdx.x; j < chunk; j += 256) srcs[j] = csr_src[base + j0 + j];
    __syncthreads();
    for (int j = 0; j < chunk; ++j){
      int s = srcs[j];
      float al = expf(lrelu_f(a_s[(size_t)s * 4 + h] + adv) - mv) * sinv;
      a += al * hs_lin[(size_t)s * HH + c];
    }
  }
  size_t o = (size_t)d * HH + c;
  if (ACCUM) acc[o] += a;
  else       acc[o] = a;
}

// ---- user epilogue: elu(acc + b1 + b2) @ W_out + b_out ; block 256, 4 rows
__global__ void out_user_kernel(const float* __restrict__ acc, const float* __restrict__ b1,
                                const float* __restrict__ b2, const float* __restrict__ Wo,
                                const float* __restrict__ bo, float* __restrict__ out, int n){
  __shared__ float tmp[4 * HH];
  int row0 = blockIdx.x * 4;
  for (int r = 0; r < 4; ++r){
    int rr = row0 + r;
    float v = 0.f;
    if (rr < n)
      v = elu_f(acc[(size_t)rr * HH + threadIdx.x] + b1[threadIdx.x] + b2[threadIdx.x]);
    tmp[r * HH + threadIdx.x] = v;
  }
  __syncthreads();
  int c = threadIdx.x & 63, g = threadIdx.x >> 6;
  float s = 0.f;
  for (int k = 0; k < HH; ++k) s += tmp[g * HH + k] * Wo[k * OUT_DIM + c];
  int rr = row0 + g;
  if (rr < n) out[(size_t)rr * OUT_DIM + c] = s + bo[c];
}

// ---- post epilogue: elementwise elu(acc + bias)
__global__ void out_post_kernel(const float* __restrict__ acc, const float* __restrict__ bias,
                                float* __restrict__ out, size_t total){
  size_t i = (size_t)blockIdx.x * blockDim.x + threadIdx.x;
  if (i >= total) return;
  out[i] = elu_f(acc[i] + bias[i & 255]);
}

extern "C" void kernel_launch(void* const* d_in, const int* in_sizes, int n_in,
                              void* d_out, int out_size, void* d_ws, size_t ws_size,
                              hipStream_t stream){
  const float* xu = (const float*)d_in[0];
  const float* xp = (const float*)d_in[1];
  const float* Wp = (const float*)d_in[8];
  const float* bp = (const float*)d_in[9];
  const float* Wo = (const float*)d_in[22];
  const float* bo = (const float*)d_in[23];

  const int n_user = in_sizes[0] / IN_DIM;
  const int n_post = in_sizes[1] / IN_DIM;
  const int n_max  = n_user > n_post ? n_user : n_post;
  int E_max = in_sizes[2];
  if (in_sizes[4] > E_max) E_max = in_sizes[4];
  if (in_sizes[6] > E_max) E_max = in_sizes[6];
  float* out = (float*)d_out;

  // workspace layout (all 4-byte elements)
  float* ws = (float*)d_ws;
  size_t off = 0;
  float* hu       = ws + off; off += (size_t)n_user * HID;
  float* hp       = ws + off; off += (size_t)n_post * HID;
  float* acc_user = ws + off; off += (size_t)n_user * HH;
  float* acc_post = ws + off; off += (size_t)n_post * HH;
  float* hs_lin   = ws + off; off += (size_t)n_max * HH;
  float* a_s      = ws + off; off += (size_t)n_max * HEADS;
  float* a_d      = ws + off; off += (size_t)n_max * HEADS;
  float* m_buf    = ws + off; off += (size_t)n_max * HEADS;
  float* s_buf    = ws + off; off += (size_t)n_max * HEADS;
  float* w_s      = ws + off; off += HH;
  float* w_d      = ws + off; off += HH;
  int* deg        = (int*)(ws + off); off += n_max;
  int* offs       = (int*)(ws + off); off += n_max;
  int* cursor     = (int*)(ws + off); off += n_max;
  int* bsum       = (int*)(ws + off); off += 256;
  int* csr_src    = (int*)(ws + off); off += E_max;

  int n_total = n_user + n_post;
  proj_kernel<<<(n_total + 15) / 16, 256, 0, stream>>>(xu, xp, Wp, bp, hu, hp, n_user, n_total);

  for (int t = 0; t < 3; ++t){
    const int*   src;  const int* dst;
    const float *lin, *att_s, *att_d;
    const float *h_src, *h_dst;
    int n_src, n_dst, E_;
    float* acc;
    if (t == 0){        // u2u -> user (write)
      src = (const int*)d_in[2]; dst = (const int*)d_in[3]; E_ = in_sizes[2];
      lin = (const float*)d_in[10]; att_s = (const float*)d_in[11]; att_d = (const float*)d_in[12];
      h_src = hu; h_dst = hu; n_src = n_user; n_dst = n_user; acc = acc_user;
    } else if (t == 1){ // p2u -> user (accumulate)
      src = (const int*)d_in[4]; dst = (const int*)d_in[5]; E_ = in_sizes[4];
      lin = (const float*)d_in[14]; att_s = (const float*)d_in[15]; att_d = (const float*)d_in[16];
      h_src = hp; h_dst = hu; n_src = n_post; n_dst = n_user; acc = acc_user;
    } else {            // u2p -> post (write)
      src = (const int*)d_in[6]; dst = (const int*)d_in[7]; E_ = in_sizes[6];
      lin = (const float*)d_in[18]; att_s = (const float*)d_in[19]; att_d = (const float*)d_in[20];
      h_src = hu; h_dst = hp; n_src = n_user; n_dst = n_post; acc = acc_post;
    }

    fold_kernel<<<1, 256, 0, stream>>>(lin, att_s, att_d, w_s, w_d);
    hslin_kernel<<<(n_src + 7) / 8, 256, 0, stream>>>(h_src, lin, hs_lin, n_src);
    att_node_kernel<<<(n_src + n_dst + 3) / 4, 256, 0, stream>>>(h_src, h_dst, w_s, w_d, a_s, a_d, n_src, n_dst);

    // CSR build
    hipMemsetAsync(deg, 0, (size_t)n_dst * sizeof(int), stream);
    hist_kernel<<<(E_ + 255) / 256, 256, 0, stream>>>(dst, deg, E_);
    int nb = (n_dst + 255) / 256;
    scan1_kernel<<<nb, 256, 0, stream>>>(deg, offs, bsum, n_dst);
    scan2_kernel<<<1, 256, 0, stream>>>(bsum, nb);
    scan3_kernel<<<nb, 256, 0, stream>>>(offs, cursor, bsum, n_dst);
    csrfill_kernel<<<(E_ + 255) / 256, 256, 0, stream>>>(src, dst, cursor, csr_src, E_);

    stats_kernel<<<(n_dst + 255) / 256, 256, 0, stream>>>(csr_src, offs, deg, a_s, a_d, m_buf, s_buf, n_dst);
    if (t == 1)
      gather_kernel<1><<<n_dst, 256, 0, stream>>>(csr_src, offs, deg, hs_lin, a_s, a_d, m_buf, s_buf, acc, n_dst);
    else
      gather_kernel<0><<<n_dst, 256, 0, stream>>>(csr_src, offs, deg, hs_lin, a_s, a_d, m_buf, s_buf, acc, n_dst);
  }

  out_user_kernel<<<(n_user + 3) / 4, 256, 0, stream>>>(
      acc_user, (const float*)d_in[13], (const float*)d_in[17], Wo, bo, out, n_user);
  out_post_kernel<<<((size_t)n_post * HH + 255) / 256, 256, 0, stream>>>(
      acc_post, (const float*)d_in[21], out + (size_t)n_user * OUT_DIM, (size_t)n_post * HH);
}